// Round 7
// baseline (13535.936 us; speedup 1.0000x reference)
//
#include <hip/hip_runtime.h>
#include <cstdint>
#include <cstddef>

// ---------------------------------------------------------------------------
// RNN_42537356100303: 3-layer tanh RNN (B=128,T=1024,F=24,H=512) + MLP head.
// Phase plan (all on one in-place f16 buffer P[B*T, 512] in ws):
//   k_cvt   : fp32 weights -> f16, bias_l = b_ih+b_hh, zero X handshake buf
//   k_xp0   : P = x @ W_ih0^T + bias0            (VALU, K=24)
//   k_scan8 : MFMA cluster scan. Rounds 0-6 proved the scan is bound by
//             AGGREGATE L2 BW redundantly streaming W to 128 WGs
//             (128 x 448 KB x 1024 / 36.9 TB/s = 1600 us = measured 1690),
//             and that W cannot be held in VGPRs (256-reg cap / remat /
//             AGPR-demotion: rounds 2,3,6). Fix: 8 clusters (16 batches)
//             x 8 slices = 64 WGs; each WG owns a 64-row W slice = 64 KB,
//             LDS-resident ONCE; B-frags hoisted to 64 VGPR (from LDS ->
//             non-remat). Per step: 16x64x512 MFMA tile (k_proj's proven
//             fragment layout), tanh, all-to-all h exchange among the 8
//             same-cluster WGs via {tag,f16} u64 relaxed-agent atomics
//             (round-1-proven protocol, ~0.14 us/step overhead), cluster
//             on one XCD via bid&7 (perf heuristic only).
//   k_proj  : P = P @ W_ih^T + bias  (in-place row-block MFMA f16 GEMM)
//   k_head  : out = silu(last @ W1^T + b1) @ W2^T + b2
// ---------------------------------------------------------------------------

typedef _Float16 half_t;
typedef __attribute__((ext_vector_type(2))) _Float16 half2_t;
typedef __attribute__((ext_vector_type(8))) _Float16 frag8;
typedef __attribute__((ext_vector_type(4))) float    frag4;

union HU16 { _Float16 h; unsigned short u; };

__device__ __forceinline__ float fast_tanh(float x) {
    float ax = __builtin_fabsf(x);
    float e  = __expf(-2.f * ax);          // v_exp_f32 path
    float r  = (1.f - e) / (1.f + e);
    return __builtin_copysignf(r, x);
}

// Barrier that does NOT drain vmcnt: LDS ops ordered (lgkmcnt(0)), global
// stores/loads stay outstanding across steps.
#define SCAN_BAR() \
    asm volatile("s_waitcnt lgkmcnt(0)\n\ts_barrier" ::: "memory")

#define WN (512 * 512)

// X exchange buffer: [par=2][cluster=8][slice=8][slot=1024] u64
#define XSLOTS (2 * 8 * 8 * 1024)

// -------------------------------------------------------------- k_cvt ------
__global__ __launch_bounds__(256) void k_cvt(
    const float* whh0, const float* whh1, const float* whh2,
    const float* wih1, const float* wih2,
    const float* bi0, const float* bh0, const float* bi1, const float* bh1,
    const float* bi2, const float* bh2,
    half_t* w16, float* bias, unsigned long long* X)
{
    int idx = blockIdx.x * 256 + threadIdx.x;
    if (idx < XSLOTS) X[idx] = 0ull;        // re-arm handshake tags (replay-safe)
    if (idx < 5 * WN) {
        int seg = idx / WN, off = idx % WN;
        const float* s = seg == 0 ? whh0 : seg == 1 ? whh1 : seg == 2 ? whh2
                       : seg == 3 ? wih1 : wih2;
        w16[idx] = (half_t)s[off];
    } else {
        int j = idx - 5 * WN;
        if (j < 3 * 512) {
            int l = j >> 9, o = j & 511;
            const float* a = l == 0 ? bi0 : l == 1 ? bi1 : bi2;
            const float* c = l == 0 ? bh0 : l == 1 ? bh1 : bh2;
            bias[j] = a[o] + c[o];
        }
    }
}

// -------------------------------------------------------------- k_xp0 ------
__global__ __launch_bounds__(256) void k_xp0(
    const float* __restrict__ x, const float* __restrict__ wih0,
    const float* __restrict__ bias0, half_t* __restrict__ P)
{
    __shared__ float wl[512 * 24];
    __shared__ float xl[32 * 25];
    int tid = threadIdx.x;
    int r0  = blockIdx.x * 32;
    for (int i = tid; i < 512 * 24; i += 256) wl[i] = wih0[i];
    for (int i = tid; i < 32 * 24; i += 256) {
        int r = i / 24, f = i % 24;
        xl[r * 25 + f] = x[(size_t)(r0 + r) * 24 + f];
    }
    __syncthreads();
    int r = tid >> 3, c = tid & 7;
    float xr[24];
#pragma unroll
    for (int f = 0; f < 24; f++) xr[f] = xl[r * 25 + f];
    size_t orow = (size_t)(r0 + r) * 512;
    for (int og = 0; og < 8; og++) {
        half_t hv[8];
#pragma unroll
        for (int oj = 0; oj < 8; oj++) {
            int o = og * 64 + c * 8 + oj;
            float acc = bias0[o];
#pragma unroll
            for (int f = 0; f < 24; f++) acc = fmaf(xr[f], wl[o * 24 + f], acc);
            hv[oj] = (half_t)acc;
        }
        *(uint4*)(P + orow + og * 64 + c * 8) = *(const uint4*)hv;
    }
}

// -------------------------------------------------------------- k_scan8 ----
// 64 WGs x 256 thr. WG bid: cluster c = bid&7 (batches [16c,16c+16), on one
// XCD under round-robin), slice s = bid>>3 (output cols [64s, 64s+64)).
// W slice LDS-resident; B-frags in 64 VGPR; A = h tile [16][520] double-buf.
// Per wave (4 waves): n-tile nt = wave (cols 16*wave..+16 of slice).
__global__ __launch_bounds__(256, 1)
void k_scan8(half_t* __restrict__ P, const half_t* __restrict__ whh,
             unsigned long long* __restrict__ X, int tag_base)
{
    extern __shared__ char smem[];
    half_t* Wl = (half_t*)smem;                   // [64][520] f16 = 66,560 B
    half_t* hl = (half_t*)(smem + 66560);         // [2][16][520] = 33,280 B

    const int tid  = threadIdx.x;
    const int bid  = blockIdx.x;
    const int c    = bid & 7;
    const int s    = bid >> 3;
    const int b0   = c * 16;
    const int scol = s * 64;

    const int wave = tid >> 6, lane = tid & 63;
    const int lm = lane & 15, lq = lane >> 4;
    const int mycol = wave * 16 + lm;             // slice-local output col

    // ---- stage W slice rows [scol, scol+64) -> LDS (once) ----
    {
        const uint4* Wg = (const uint4*)(whh + (size_t)scol * 512);
        for (int u = tid; u < 4096; u += 256) {
            int r = u >> 6, col = u & 63;
            *(uint4*)(Wl + r * 520 + col * 8) = Wg[(size_t)r * 64 + col];
        }
    }
    for (int i = tid; i < 2 * 16 * 520; i += 256) hl[i] = (_Float16)0.f;
    __syncthreads();

    // ---- B fragments -> registers (from LDS: non-rematerializable) ----
    frag8 bf[16];
#pragma unroll
    for (int kb = 0; kb < 16; kb++)
        bf[kb] = *(const frag8*)(Wl + mycol * 520 + kb * 32 + lq * 8);

    // per-lane P row pointers (4 accumulator rows), at col scol+mycol
    half_t* prow[4];
#pragma unroll
    for (int i = 0; i < 4; i++)
        prow[i] = P + ((size_t)(b0 + lq * 4 + i) * 1024) * 512 + scol + mycol;

    float xpc[4];
#pragma unroll
    for (int i = 0; i < 4; i++) xpc[i] = (float)prow[i][0];   // xp_0

    // poll geometry: this thread's 4 slots per peer
    const int j0 = tid * 4;
    const int ri = j0 >> 6, cj = j0 & 63;       // row 0..15, col base 0..60

    int cur = 0;
    for (int t = 0; t < 1024; ++t) {
        half_t* hc = hl + cur * (16 * 520);
        half_t* hn = hl + (cur ^ 1) * (16 * 520);
        int tn = t + 1 < 1024 ? t + 1 : 1023;

        float xpn[4];
#pragma unroll
        for (int i = 0; i < 4; i++)             // prefetch next xp
            xpn[i] = (float)prow[i][(size_t)tn * 512];

        // ---- MFMA: acc[16 x 16] = h_prev(16x512) @ Wslice_nt^T ----
        frag4 acc0 = {0.f, 0.f, 0.f, 0.f};
        frag4 acc1 = {0.f, 0.f, 0.f, 0.f};
#pragma unroll
        for (int kb = 0; kb < 16; kb += 2) {    // 2 chains: break dep latency
            frag8 af0 = *(const frag8*)(hc + lm * 520 + kb * 32 + lq * 8);
            frag8 af1 = *(const frag8*)(hc + lm * 520 + (kb + 1) * 32 + lq * 8);
            acc0 = __builtin_amdgcn_mfma_f32_16x16x32_f16(af0, bf[kb],     acc0, 0, 0, 0);
            acc1 = __builtin_amdgcn_mfma_f32_16x16x32_f16(af1, bf[kb + 1], acc1, 0, 0, 0);
        }

        // ---- tanh, publish, own-LDS, P-store ----
        unsigned need = (unsigned)(tag_base + t + 1);
        unsigned long long* Xpub =
            X + ((((size_t)(t & 1) * 8 + c) * 8 + s) << 10);
#pragma unroll
        for (int i = 0; i < 4; i++) {
            float hv = fast_tanh(acc0[i] + acc1[i] + xpc[i]);
            _Float16 hh = (_Float16)hv;
            HU16 hu; hu.h = hh;
            unsigned long long pk =
                ((unsigned long long)need << 32) | (unsigned long long)hu.u;
            __hip_atomic_store(&Xpub[(lq * 4 + i) * 64 + mycol], pk,
                               __ATOMIC_RELAXED, __HIP_MEMORY_SCOPE_AGENT);
            hn[(lq * 4 + i) * 520 + scol + mycol] = hh;     // own slice
            prow[i][(size_t)t * 512] = hh;       // in-place over xp, in flight
        }

        // ---- gather peers' slices of h_t into hn ----
        if (t < 1023) {
            const unsigned long long* Xpar =
                X + (((size_t)(t & 1) * 8 + c) << 13);      // cluster base
            unsigned long long v[7][4];
#pragma unroll
            for (int pi = 0; pi < 7; pi++) {                // issue all 28
                int peer = pi + (pi >= s ? 1 : 0);
                const unsigned long long* Xp = Xpar + (peer << 10) + j0;
#pragma unroll
                for (int q = 0; q < 4; q++)
                    v[pi][q] = __hip_atomic_load(&Xp[q],
                                   __ATOMIC_RELAXED, __HIP_MEMORY_SCOPE_AGENT);
            }
#pragma unroll
            for (int pi = 0; pi < 7; pi++) {                // verify + retry
                int peer = pi + (pi >= s ? 1 : 0);
                const unsigned long long* Xp = Xpar + (peer << 10) + j0;
                unsigned short h4[4];
#pragma unroll
                for (int q = 0; q < 4; q++) {
                    unsigned long long vv = v[pi][q];
                    while ((unsigned)(vv >> 32) < need)
                        vv = __hip_atomic_load(&Xp[q],
                                 __ATOMIC_RELAXED, __HIP_MEMORY_SCOPE_AGENT);
                    h4[q] = (unsigned short)vv;
                }
                *(unsigned long long*)(hn + ri * 520 + peer * 64 + cj) =
                    *(const unsigned long long*)h4;
            }
        }
        SCAN_BAR();                              // lgkm-only; vmem in flight
        cur ^= 1;
#pragma unroll
        for (int i = 0; i < 4; i++) xpc[i] = xpn[i];
    }
}

// -------------------------------------------------------------- k_proj -----
// In-place row-block GEMM: rows [r0, r0+64) of P times W^T (W = [512 o][512 k]
// f16), + bias, overwrite. MFMA f32_16x16x32_f16.
__global__ __launch_bounds__(256, 2) void k_proj(
    half_t* __restrict__ P, const half_t* __restrict__ w16,
    const float* __restrict__ bias)
{
    extern __shared__ char smem[];
    half_t* A = (half_t*)smem;                  // 64 rows x stride 520 (65 KB)
    const int AS = 520;
    int tid = threadIdx.x;
    size_t r0 = (size_t)blockIdx.x * 64;

    const uint4* Pg = (const uint4*)(P + r0 * 512);
    for (int u = tid; u < 4096; u += 256) {     // 64 rows x 64 uint4
        uint4 v = Pg[u];
        int row = u >> 6, col = u & 63;
        *(uint4*)(A + row * AS + col * 8) = v;
    }
    __syncthreads();

    int wave = tid >> 6, lane = tid & 63;
    int lm = lane & 15, lq = lane >> 4;

    frag4 acc[4][8];
#pragma unroll
    for (int mt = 0; mt < 4; mt++)
#pragma unroll
        for (int nt = 0; nt < 8; nt++) acc[mt][nt] = (frag4){0.f, 0.f, 0.f, 0.f};

    for (int kb = 0; kb < 16; kb++) {
        int k0 = kb * 32 + lq * 8;
        frag8 af[4];
#pragma unroll
        for (int mt = 0; mt < 4; mt++)
            af[mt] = *(const frag8*)(A + (mt * 16 + lm) * AS + k0);
        frag8 bf[8];
#pragma unroll
        for (int nt = 0; nt < 8; nt++) {
            int n = wave * 128 + nt * 16 + lm;
            bf[nt] = *(const frag8*)(w16 + (size_t)n * 512 + k0);
        }
#pragma unroll
        for (int mt = 0; mt < 4; mt++)
#pragma unroll
            for (int nt = 0; nt < 8; nt++)
                acc[mt][nt] = __builtin_amdgcn_mfma_f32_16x16x32_f16(
                    af[mt], bf[nt], acc[mt][nt], 0, 0, 0);
    }

#pragma unroll
    for (int mt = 0; mt < 4; mt++) {
        int row = mt * 16 + lq * 4;
#pragma unroll
        for (int nt = 0; nt < 8; nt++) {
            int oc = wave * 128 + nt * 16 + lm;
            float bo = bias[oc];
#pragma unroll
            for (int i = 0; i < 4; i++) {
                float v = acc[mt][nt][i] + bo;
                P[(r0 + row + i) * 512 + oc] = (half_t)v;
            }
        }
    }
}

// -------------------------------------------------------------- k_head -----
__global__ __launch_bounds__(256) void k_head(
    const half_t* __restrict__ P, const float* __restrict__ W1,
    const float* __restrict__ b1, const float* __restrict__ W2,
    const float* __restrict__ b2, float* __restrict__ out)
{
    __shared__ float lastv[512];
    __shared__ float zl[1024];
    __shared__ float red[8][33];
    int tid = threadIdx.x, b = blockIdx.x;
    const half_t* lr = P + ((size_t)b * 1024 + 1023) * 512;
    lastv[tid]       = (float)lr[tid];
    lastv[tid + 256] = (float)lr[tid + 256];
    __syncthreads();
#pragma unroll
    for (int i = 0; i < 4; i++) {
        int m = tid + 256 * i;
        const float* wr = W1 + (size_t)m * 512;
        float acc = b1[m];
        for (int k = 0; k < 512; k += 4) {
            float4 wv = *(const float4*)(wr + k);
            acc = fmaf(wv.x, lastv[k],     acc);
            acc = fmaf(wv.y, lastv[k + 1], acc);
            acc = fmaf(wv.z, lastv[k + 2], acc);
            acc = fmaf(wv.w, lastv[k + 3], acc);
        }
        zl[m] = acc / (1.f + __expf(-acc));         // silu
    }
    __syncthreads();
    int c = tid & 7, mc = tid >> 3;                 // 8 outputs x 32 m-chunks
    float p = 0.f;
#pragma unroll
    for (int j = 0; j < 32; j++) {
        int m = mc * 32 + j;
        p = fmaf(zl[m], W2[c * 1024 + m], p);
    }
    red[c][mc] = p;
    __syncthreads();
    if (tid < 8) {
        float s = b2[tid];
#pragma unroll
        for (int j = 0; j < 32; j++) s += red[tid][j];
        out[b * 8 + tid] = s;
    }
}

// ---------------------------------------------------------------------------
extern "C" void kernel_launch(void* const* d_in, const int* in_sizes, int n_in,
                              void* d_out, int out_size, void* d_ws, size_t ws_size,
                              hipStream_t stream)
{
    const float* x    = (const float*)d_in[0];
    const float* wih0 = (const float*)d_in[1];
    const float* whh0 = (const float*)d_in[2];
    const float* bi0  = (const float*)d_in[3];
    const float* bh0  = (const float*)d_in[4];
    const float* wih1 = (const float*)d_in[5];
    const float* whh1 = (const float*)d_in[6];
    const float* bi1  = (const float*)d_in[7];
    const float* bh1  = (const float*)d_in[8];
    const float* wih2 = (const float*)d_in[9];
    const float* whh2 = (const float*)d_in[10];
    const float* bi2  = (const float*)d_in[11];
    const float* bh2  = (const float*)d_in[12];
    const float* W1   = (const float*)d_in[13];
    const float* b1   = (const float*)d_in[14];
    const float* W2   = (const float*)d_in[15];
    const float* b2   = (const float*)d_in[16];
    float* out = (float*)d_out;

    char* ws = (char*)d_ws;
    half_t* P    = (half_t*)ws;                               // 134,217,728 B
    half_t* W16  = (half_t*)(ws + 134217728);                 //   2,621,440 B
    float*  bias = (float*)(ws + 134217728 + 2621440);        //       6,144 B
    unsigned long long* X =
        (unsigned long long*)(ws + 134217728 + 2621440 + 8192);  // 1,048,576 B

    // dynamic-LDS opt-in (>64 KB); idempotent, not a stream op
    hipFuncSetAttribute((const void*)k_scan8,
                        hipFuncAttributeMaxDynamicSharedMemorySize, 99840);
    hipFuncSetAttribute((const void*)k_proj,
                        hipFuncAttributeMaxDynamicSharedMemorySize, 66560);

    k_cvt<<<5126, 256, 0, stream>>>(whh0, whh1, whh2, wih1, wih2,
                                    bi0, bh0, bi1, bh1, bi2, bh2, W16, bias, X);
    k_xp0<<<4096, 256, 0, stream>>>(x, wih0, bias, P);
    k_scan8<<<64, 256, 99840, stream>>>(P, W16 + 0 * WN, X, 0);
    k_proj<<<2048, 256, 66560, stream>>>(P, W16 + 3 * WN, bias + 512);
    k_scan8<<<64, 256, 99840, stream>>>(P, W16 + 1 * WN, X, 1024);
    k_proj<<<2048, 256, 66560, stream>>>(P, W16 + 4 * WN, bias + 1024);
    k_scan8<<<64, 256, 99840, stream>>>(P, W16 + 2 * WN, X, 2048);
    k_head<<<128, 256, 0, stream>>>(P, W1, b1, W2, b2, out);
}